// Round 2
// baseline (254.175 us; speedup 1.0000x reference)
//
#include <hip/hip_runtime.h>
#include <math.h>

#define BB 32
#define PP 2048
#define CC 512
#define TT 128            // PP/16
#define TB 16             // t-slices owned per block
#define HALO_ROWS ((TB + 2) * 16)   // 288 (own + 1-slice halo each side)
#define OWN_ROWS  (TB * 16)         // 256

typedef float f4_t __attribute__((ext_vector_type(4)));

// One block per (b, t-chunk). 1024 threads = 16 waves.
// Phase 1: means for t in [t0-1, t0+TB] (halo recompute, no grid sync).
// Phase 2: 27-tap merged stencil + sigmoid -> LDS gates.
// Phase 3: re-read own rows (L2/L3-warm), scale, non-temporal store.
__global__ __launch_bounds__(1024) void fused_kernel(
        const float* __restrict__ x,
        const float* __restrict__ w1, const float* __restrict__ w2,
        const float* __restrict__ w3, float* __restrict__ out) {
    __shared__ float lmean[HALO_ROWS];   // indexed (t - t0 + 1)*16 + h*4 + w
    __shared__ float lgate[OWN_ROWS];

    int blk  = blockIdx.x;
    int b    = blk >> 3;            // 8 chunks per batch
    int t0   = (blk & 7) * TB;
    int wave = threadIdx.x >> 6;
    int lane = threadIdx.x & 63;
    const size_t xbase = (size_t)b * (PP * CC);

    // ---- Phase 1: 288 halo+own row means, 18 rows per wave ----
    #pragma unroll
    for (int rr = 0; rr < 18; ++rr) {
        int r = wave * 18 + rr;             // 0..287
        int t = t0 - 1 + (r >> 4);
        if (t < 0 || t >= TT) continue;     // wave-uniform skip at edges
        int p = t * 16 + (r & 15);
        const float4* xr = (const float4*)(x + xbase + (size_t)p * CC);
        float4 va = xr[lane];
        float4 vb = xr[lane + 64];
        float s = (va.x + va.y) + (va.z + va.w) + (vb.x + vb.y) + (vb.z + vb.w);
        #pragma unroll
        for (int off = 32; off; off >>= 1) s += __shfl_down(s, off, 64);
        if (lane == 0) lmean[r] = s * (1.0f / 512.0f);
    }
    __syncthreads();

    // ---- Phase 2: gates for own 256 rows ----
    if (threadIdx.x < OWN_ROWS) {
        int i  = threadIdx.x;
        int tl = i >> 4;                 // 0..15
        int h  = (i >> 2) & 3;
        int w  = i & 3;
        int tg = t0 + tl;                // global t
        float g = 0.0f;
        #pragma unroll
        for (int ii = 0; ii < 3; ++ii) {
            int tt = tg + ii - 1;
            if (tt < 0 || tt >= TT) continue;
            #pragma unroll
            for (int jj = 0; jj < 3; ++jj) {
                int hh = h + jj - 1;
                if (hh < 0 || hh >= 4) continue;
                #pragma unroll
                for (int kk = 0; kk < 3; ++kk) {
                    int ww = w + kk - 1;
                    if (ww < 0 || ww >= 4) continue;
                    float wt = w3[ii * 9 + jj * 3 + kk];
                    if (ii < 2 && jj < 2 && kk < 2) wt += w2[ii * 4 + jj * 2 + kk];
                    if (ii == 1 && jj == 1 && kk == 1) wt += w1[0];
                    g += wt * lmean[(tl + ii) * 16 + hh * 4 + ww];
                }
            }
        }
        lgate[i] = 1.0f / (1.0f + __expf(-g));
    }
    __syncthreads();

    // ---- Phase 3: scale own rows, 16 rows per wave ----
    #pragma unroll
    for (int rr = 0; rr < 16; ++rr) {
        int i = wave * 16 + rr;          // own row 0..255
        int p = t0 * 16 + i;
        float gg = lgate[i];
        const float4* xr = (const float4*)(x + xbase + (size_t)p * CC);
        f4_t* orow = (f4_t*)(out + xbase + (size_t)p * CC);
        float4 va = xr[lane];
        float4 vb = xr[lane + 64];
        f4_t ra = { va.x * gg, va.y * gg, va.z * gg, va.w * gg };
        f4_t rb = { vb.x * gg, vb.y * gg, vb.z * gg, vb.w * gg };
        __builtin_nontemporal_store(ra, &orow[lane]);
        __builtin_nontemporal_store(rb, &orow[lane + 64]);
    }
}

extern "C" void kernel_launch(void* const* d_in, const int* in_sizes, int n_in,
                              void* d_out, int out_size, void* d_ws, size_t ws_size,
                              hipStream_t stream) {
    const float* x  = (const float*)d_in[0];
    const float* w1 = (const float*)d_in[1];
    const float* w2 = (const float*)d_in[2];
    const float* w3 = (const float*)d_in[3];
    float* out = (float*)d_out;

    fused_kernel<<<BB * (TT / TB), 1024, 0, stream>>>(x, w1, w2, w3, out);
}

// Round 3
// 251.806 us; speedup vs baseline: 1.0094x; 1.0094x over previous
//
#include <hip/hip_runtime.h>
#include <math.h>

#define BB 32
#define PP 2048
#define CC 512
#define TT 128                      // PP/16
#define TB 8                        // t-slices owned per block
#define HALO_ROWS ((TB + 2) * 16)   // 160
#define OWN_ROWS  (TB * 16)         // 128

typedef float f4_t __attribute__((ext_vector_type(4)));

// One block per (b, t-chunk): 512 threads = 8 waves, 512 blocks (2/CU).
// Phase 1: means for t in [t0-1, t0+TB] (halo recompute). Half-wave per row:
//          32 lanes x 4 float4 each = 512 floats, 5-level shuffle tree.
// Phase 2: 27-tap merged stencil + sigmoid -> LDS gates (threads 0..127).
// Phase 3: re-read own rows (L2/L3-warm), scale, non-temporal store.
__global__ __launch_bounds__(512, 4) void fused_kernel(
        const float* __restrict__ x,
        const float* __restrict__ w1, const float* __restrict__ w2,
        const float* __restrict__ w3, float* __restrict__ out) {
    __shared__ float lmean[HALO_ROWS];
    __shared__ float lgate[OWN_ROWS];

    int blk  = blockIdx.x;
    int b    = blk >> 4;             // 16 chunks per batch
    int t0   = (blk & 15) * TB;
    int wave = threadIdx.x >> 6;     // 0..7
    int lane = threadIdx.x & 63;
    int half = lane >> 5;            // 0/1: which of the 2 rows this step
    int c    = lane & 31;            // column group within row
    const size_t xbase = (size_t)b * (PP * CC);

    // ---- Phase 1: 160 halo+own row means, 20 rows per wave, 2 rows/step ----
    int rbase = wave * 20;
    #pragma unroll
    for (int it = 0; it < 10; ++it) {
        int r = rbase + it * 2 + half;        // 0..159
        int t = t0 - 1 + (r >> 4);
        bool ok = (t >= 0) && (t < TT);
        int tc = ok ? t : 0;                  // clamp: load real memory, zero later
        int p  = tc * 16 + (r & 15);
        const float4* xr = (const float4*)(x + xbase + (size_t)p * CC);
        float4 v0 = xr[c];
        float4 v1 = xr[c + 32];
        float4 v2 = xr[c + 64];
        float4 v3 = xr[c + 96];
        float s = ((v0.x + v0.y) + (v0.z + v0.w)) + ((v1.x + v1.y) + (v1.z + v1.w))
                + ((v2.x + v2.y) + (v2.z + v2.w)) + ((v3.x + v3.y) + (v3.z + v3.w));
        #pragma unroll
        for (int off = 16; off; off >>= 1) s += __shfl_down(s, off, 64);
        if (c == 0) lmean[r] = ok ? s * (1.0f / 512.0f) : 0.0f;
    }
    __syncthreads();

    // ---- Phase 2: gates for own 128 rows ----
    if (threadIdx.x < OWN_ROWS) {
        int i  = threadIdx.x;
        int tl = i >> 4;                 // 0..TB-1
        int h  = (i >> 2) & 3;
        int w  = i & 3;
        int tg = t0 + tl;                // global t
        float g = 0.0f;
        #pragma unroll
        for (int ii = 0; ii < 3; ++ii) {
            int tt = tg + ii - 1;
            if (tt < 0 || tt >= TT) continue;
            #pragma unroll
            for (int jj = 0; jj < 3; ++jj) {
                int hh = h + jj - 1;
                if (hh < 0 || hh >= 4) continue;
                #pragma unroll
                for (int kk = 0; kk < 3; ++kk) {
                    int ww = w + kk - 1;
                    if (ww < 0 || ww >= 4) continue;
                    float wt = w3[ii * 9 + jj * 3 + kk];
                    if (ii < 2 && jj < 2 && kk < 2) wt += w2[ii * 4 + jj * 2 + kk];
                    if (ii == 1 && jj == 1 && kk == 1) wt += w1[0];
                    g += wt * lmean[(tl + ii) * 16 + hh * 4 + ww];
                }
            }
        }
        lgate[i] = 1.0f / (1.0f + __expf(-g));
    }
    __syncthreads();

    // ---- Phase 3: scale own 128 rows, 16 rows per wave ----
    #pragma unroll
    for (int rr = 0; rr < 16; ++rr) {
        int i = wave * 16 + rr;          // own row 0..127
        int p = t0 * 16 + i;
        float gg = lgate[i];
        const float4* xr = (const float4*)(x + xbase + (size_t)p * CC);
        f4_t* orow = (f4_t*)(out + xbase + (size_t)p * CC);
        float4 va = xr[lane];
        float4 vb = xr[lane + 64];
        f4_t ra = { va.x * gg, va.y * gg, va.z * gg, va.w * gg };
        f4_t rb = { vb.x * gg, vb.y * gg, vb.z * gg, vb.w * gg };
        __builtin_nontemporal_store(ra, &orow[lane]);
        __builtin_nontemporal_store(rb, &orow[lane + 64]);
    }
}

extern "C" void kernel_launch(void* const* d_in, const int* in_sizes, int n_in,
                              void* d_out, int out_size, void* d_ws, size_t ws_size,
                              hipStream_t stream) {
    const float* x  = (const float*)d_in[0];
    const float* w1 = (const float*)d_in[1];
    const float* w2 = (const float*)d_in[2];
    const float* w3 = (const float*)d_in[3];
    float* out = (float*)d_out;

    fused_kernel<<<BB * (TT / TB), 512, 0, stream>>>(x, w1, w2, w3, out);
}